// Round 3
// baseline (113.748 us; speedup 1.0000x reference)
//
#include <hip/hip_runtime.h>
#include <hip/hip_bf16.h>

#define B_ROWS 4096
#define NROWS  8192   // 2B
#define D      256
#define TT     264    // tiles per strip-pair (32-col tiles)
#define NBLK2  1024   // 16 pairs * 32 segments * 2 half-panels

typedef __attribute__((ext_vector_type(8))) short bf16x8;
typedef __attribute__((ext_vector_type(4))) float floatx4;

// ---------------------------------------------------------------------------
// Kernel 1: fused normalize + pos + selfdot + zero-init rowsum/out/counter.
// ---------------------------------------------------------------------------
__global__ __launch_bounds__(256) void norm_pos_kernel(
    const float* __restrict__ xi, const float* __restrict__ xj,
    short* __restrict__ z, float* __restrict__ pos,
    float* __restrict__ selfdot, float* __restrict__ rowsum,
    float* __restrict__ out, unsigned int* __restrict__ counter) {
    int gt = blockIdx.x * 256 + threadIdx.x;
    if (gt < NROWS) rowsum[gt] = 0.f;
    if (gt == 0) { out[0] = 0.f; counter[0] = 0u; }

    int p    = blockIdx.x * 4 + (threadIdx.x >> 6);
    int lane = threadIdx.x & 63;
    float4 v1 = ((const float4*)(xi + (size_t)p * D))[lane];
    float4 v2 = ((const float4*)(xj + (size_t)p * D))[lane];
    float ss1 = v1.x * v1.x + v1.y * v1.y + v1.z * v1.z + v1.w * v1.w;
    float ss2 = v2.x * v2.x + v2.y * v2.y + v2.z * v2.z + v2.w * v2.w;
#pragma unroll
    for (int off = 32; off > 0; off >>= 1) {
        ss1 += __shfl_xor(ss1, off);
        ss2 += __shfl_xor(ss2, off);
    }
    float sc1 = 1.0f / fmaxf(sqrtf(ss1), 1e-12f);
    float sc2 = 1.0f / fmaxf(sqrtf(ss2), 1e-12f);

    union { __hip_bfloat16 h[4]; short4 s4; } u1, u2;
    u1.h[0] = __float2bfloat16(v1.x * sc1); u1.h[1] = __float2bfloat16(v1.y * sc1);
    u1.h[2] = __float2bfloat16(v1.z * sc1); u1.h[3] = __float2bfloat16(v1.w * sc1);
    u2.h[0] = __float2bfloat16(v2.x * sc2); u2.h[1] = __float2bfloat16(v2.y * sc2);
    u2.h[2] = __float2bfloat16(v2.z * sc2); u2.h[3] = __float2bfloat16(v2.w * sc2);
    ((short4*)(z + (size_t)p * D))[lane]            = u1.s4;
    ((short4*)(z + (size_t)(p + B_ROWS) * D))[lane] = u2.s4;

    float sd1 = 0.f, sd2 = 0.f, dp = 0.f;
#pragma unroll
    for (int j = 0; j < 4; j++) {
        float a = __bfloat162float(u1.h[j]);
        float b = __bfloat162float(u2.h[j]);
        sd1 += a * a; sd2 += b * b; dp += a * b;
    }
#pragma unroll
    for (int off = 32; off > 0; off >>= 1) {
        sd1 += __shfl_xor(sd1, off);
        sd2 += __shfl_xor(sd2, off);
        dp  += __shfl_xor(dp,  off);
    }
    if (lane == 0) {
        pos[p] = dp; pos[p + B_ROWS] = dp;
        selfdot[p] = sd1; selfdot[p + B_ROWS] = sd2;
    }
}

// ---------------------------------------------------------------------------
// Kernel 2 v2: half-panel blocks for 2x occupancy + async global_load_lds
// staging.
//   grid = 16 strip-pairs * 32 segments * 2 half-panels = 1024 blocks
//   block = 256 threads (4 waves), wave owns 32 rows (a[8][2] = 64 VGPRs)
//   -> ~115 regs/wave => 4 waves/SIMD (4 independent blocks/CU), vs 2 before.
// B tile (32 cols x 256 K = 16 KB) double-buffered in LDS via
// __builtin_amdgcn_global_load_lds width=16: LDS dest linear
// (wave base + lane*16), swizzle u(col,c16)=col*32+(c16^(col&7)) applied by
// pre-swizzling the per-lane GLOBAL source (m173 pattern); ds_read side keeps
// the identical formula as the verified round-0 kernel.
// ---------------------------------------------------------------------------
__global__ __launch_bounds__(256, 4) void sim_rowsum_kernel(
    const short* __restrict__ z, float* __restrict__ rowsum,
    const float* __restrict__ pos, const float* __restrict__ selfdot,
    unsigned int* __restrict__ counter, float* __restrict__ out) {
    __shared__ __align__(16) short Bbuf[2][8192];   // 2 x 16 KB
    __shared__ unsigned int done_s;
    __shared__ float sdata[4];

    const int tid  = threadIdx.x;
    const int lane = tid & 63;
    const int w    = tid >> 6;
    const int lm   = lane & 15;
    const int lg   = lane >> 4;
    const int fxor = lm & 7;

    const int bid = blockIdx.x;
    const int s   = bid >> 6;           // strip-pair 0..15
    const int q   = (bid >> 1) & 31;    // segment 0..31
    const int h   = bid & 1;            // half-panel 0..1
    const int L0  = 256 - 8 * s;        // tiles in first strip (panel s)
    const int cb  = (q * TT) >> 5;
    const int ce  = ((q + 1) * TT) >> 5;

    bf16x8 a[8][2];                     // A half-panel: 32 rows x 256 K (64 VGPRs)
    floatx4 acc[2][2];
    float rsacc[2][4];

#pragma unroll
    for (int mi = 0; mi < 2; mi++)
#pragma unroll
        for (int r = 0; r < 4; r++) rsacc[mi][r] = 0.f;

    // ---- decode tile c -> (panel, colbase, mirror) ----
    auto decode = [&](int c, int& panel, int& colbase, bool& mirror) {
        int cloc;
        if (c < L0) { panel = s;      cloc = c; }
        else        { panel = 31 - s; cloc = c - L0; }
        colbase = panel * 256 + cloc * 32;
        mirror  = (cloc >= 8);
    };

    auto decodeCol = [&](int c) {
        int cloc, panel;
        if (c < L0) { panel = s;      cloc = c; }
        else        { panel = 31 - s; cloc = c - L0; }
        return panel * 256 + cloc * 32;
    };

    auto loadA = [&](int panel) {
#pragma unroll
        for (int kk = 0; kk < 8; kk++)
#pragma unroll
            for (int mi = 0; mi < 2; mi++)
                a[kk][mi] = *(const bf16x8*)(
                    z + (size_t)(panel * 256 + h * 128 + w * 32 + mi * 16 + lm) * D +
                    kk * 32 + lg * 8);
    };

    auto flushRs = [&](int panel) {
#pragma unroll
        for (int mi = 0; mi < 2; mi++)
#pragma unroll
            for (int r = 0; r < 4; r++) {
                float v = rsacc[mi][r];
                v += __shfl_xor(v, 1); v += __shfl_xor(v, 2);
                v += __shfl_xor(v, 4); v += __shfl_xor(v, 8);
                if (lm == 0)
                    atomicAdd(&rowsum[panel * 256 + h * 128 + w * 32 + mi * 16 +
                                      lg * 4 + r], v);
                rsacc[mi][r] = 0.f;
            }
    };

    // async stage: 4 x 1KB per wave; LDS dest linear, source pre-swizzled so
    // LDS unit u = col*32 + (c16 ^ (col&7)) holds data[col][c16].
    auto stage = [&](int buf, int colbase) {
#pragma unroll
        for (int j = 0; j < 4; j++) {
            int col = w * 8 + j * 2 + (lane >> 5);
            int c16 = (lane & 31) ^ (col & 7);
            const short* src = z + (size_t)(colbase + col) * D + c16 * 8;
            __builtin_amdgcn_global_load_lds(
                (const __attribute__((address_space(1))) unsigned int*)src,
                (__attribute__((address_space(3))) unsigned int*)
                    &Bbuf[buf][(w * 4 + j) * 512],
                16, 0, 0);
        }
    };

    // ---- prologue: stage first tile, load A half-panel ----
    int panel, colbase; bool mirror;
    decode(cb, panel, colbase, mirror);
    int curpanel = panel;
    stage(0, colbase);
    loadA(panel);
    __syncthreads();

    for (int c = cb; c < ce; c++) {
        const int buf = (c - cb) & 1;
        decode(c, panel, colbase, mirror);

        if (c + 1 < ce)                   // prefetch next tile into other buffer
            stage(buf ^ 1, decodeCol(c + 1));

        if (panel != curpanel) {          // strip change (<=1 per block)
            flushRs(curpanel);
            loadA(panel);
            curpanel = panel;
        }

#pragma unroll
        for (int mi = 0; mi < 2; mi++)
#pragma unroll
            for (int ni = 0; ni < 2; ni++)
                acc[mi][ni] = (floatx4){0.f, 0.f, 0.f, 0.f};

#pragma unroll
        for (int kk = 0; kk < 8; kk++) {
            bf16x8 b0 = *(const bf16x8*)(
                &Bbuf[buf][((lm) * 32 + ((kk * 4 + lg) ^ fxor)) * 8]);
            bf16x8 b1 = *(const bf16x8*)(
                &Bbuf[buf][((16 + lm) * 32 + ((kk * 4 + lg) ^ fxor)) * 8]);
            acc[0][0] = __builtin_amdgcn_mfma_f32_16x16x32_bf16(
                a[kk][0], b0, acc[0][0], 0, 0, 0);
            acc[1][0] = __builtin_amdgcn_mfma_f32_16x16x32_bf16(
                a[kk][1], b0, acc[1][0], 0, 0, 0);
            acc[0][1] = __builtin_amdgcn_mfma_f32_16x16x32_bf16(
                a[kk][0], b1, acc[0][1], 0, 0, 0);
            acc[1][1] = __builtin_amdgcn_mfma_f32_16x16x32_bf16(
                a[kk][1], b1, acc[1][1], 0, 0, 0);
        }

        // epilogue: exp(2*sim) -> register row-sums (+ mirror col-sums)
        float cs0 = 0.f, cs1 = 0.f;
#pragma unroll
        for (int mi = 0; mi < 2; mi++)
#pragma unroll
            for (int r = 0; r < 4; r++) {
                float e0 = __expf(2.0f * acc[mi][0][r]);
                float e1 = __expf(2.0f * acc[mi][1][r]);
                rsacc[mi][r] += e0 + e1;
                cs0 += e0; cs1 += e1;
            }
        if (mirror) {
            cs0 += __shfl_xor(cs0, 16); cs0 += __shfl_xor(cs0, 32);
            cs1 += __shfl_xor(cs1, 16); cs1 += __shfl_xor(cs1, 32);
            if (lane < 16) {
                atomicAdd(&rowsum[colbase + lane],      cs0);
                atomicAdd(&rowsum[colbase + 16 + lane], cs1);
            }
        }

        __syncthreads();   // drains prefetch gloads; guards buf reuse
    }
    flushRs(curpanel);

    // ---- last-block-done: final loss ----
    __syncthreads();
    if (tid == 0) {
        __threadfence();
        done_s = atomicAdd(counter, 1u);
    }
    __syncthreads();
    if (done_s == (unsigned int)(NBLK2 - 1)) {
        __threadfence();
        float acc_l = 0.f;
#pragma unroll 4
        for (int r = tid; r < NROWS; r += 256) {
            float rsv = __hip_atomic_load(&rowsum[r], __ATOMIC_RELAXED,
                                          __HIP_MEMORY_SCOPE_AGENT);
            float denom = rsv - __expf(2.0f * selfdot[r]);
            acc_l += -2.0f * pos[r] + logf(denom);
        }
#pragma unroll
        for (int off = 32; off > 0; off >>= 1) acc_l += __shfl_xor(acc_l, off);
        if (lane == 0) sdata[w] = acc_l;
        __syncthreads();
        if (tid == 0)
            out[0] = (sdata[0] + sdata[1] + sdata[2] + sdata[3]) / (float)NROWS;
    }
}

// ---------------------------------------------------------------------------
extern "C" void kernel_launch(void* const* d_in, const int* in_sizes, int n_in,
                              void* d_out, int out_size, void* d_ws, size_t ws_size,
                              hipStream_t stream) {
    const float* xi = (const float*)d_in[0];
    const float* xj = (const float*)d_in[1];
    float* out      = (float*)d_out;

    char* ws        = (char*)d_ws;
    short* z        = (short*)ws;                             // 4 MiB
    float* rowsum   = (float*)(ws + (size_t)NROWS * D * 2);   // 32 KiB
    float* pos      = rowsum + NROWS;                         // 32 KiB
    float* selfdot  = pos + NROWS;                            // 32 KiB
    unsigned int* counter = (unsigned int*)(selfdot + NROWS);

    norm_pos_kernel<<<B_ROWS / 4, 256, 0, stream>>>(xi, xj, z, pos, selfdot,
                                                    rowsum, out, counter);
    sim_rowsum_kernel<<<NBLK2, 256, 0, stream>>>(z, rowsum, pos, selfdot,
                                                 counter, out);
}

// Round 5
// 103.729 us; speedup vs baseline: 1.0966x; 1.0966x over previous
//
#include <hip/hip_runtime.h>
#include <hip/hip_bf16.h>

#define B_ROWS 4096
#define NROWS  8192   // 2B
#define D      256
#define TT     264    // tiles per strip-pair (32-col tiles)
#define NBLK2  512    // 16 pairs * 32 segments
#define MAXT   9      // max tiles per segment (ceil(264/32)+1)

typedef __attribute__((ext_vector_type(8))) short bf16x8;
typedef __attribute__((ext_vector_type(4))) float floatx4;

// ---------------------------------------------------------------------------
// Kernel 1: fused normalize + pos + selfdot + zero-init rowsum/out/counter.
// ---------------------------------------------------------------------------
__global__ __launch_bounds__(256) void norm_pos_kernel(
    const float* __restrict__ xi, const float* __restrict__ xj,
    short* __restrict__ z, float* __restrict__ pos,
    float* __restrict__ selfdot, float* __restrict__ rowsum,
    float* __restrict__ out, unsigned int* __restrict__ counter) {
    int gt = blockIdx.x * 256 + threadIdx.x;
    if (gt < NROWS) rowsum[gt] = 0.f;
    if (gt == 0) { out[0] = 0.f; counter[0] = 0u; }

    int p    = blockIdx.x * 4 + (threadIdx.x >> 6);
    int lane = threadIdx.x & 63;
    float4 v1 = ((const float4*)(xi + (size_t)p * D))[lane];
    float4 v2 = ((const float4*)(xj + (size_t)p * D))[lane];
    float ss1 = v1.x * v1.x + v1.y * v1.y + v1.z * v1.z + v1.w * v1.w;
    float ss2 = v2.x * v2.x + v2.y * v2.y + v2.z * v2.z + v2.w * v2.w;
#pragma unroll
    for (int off = 32; off > 0; off >>= 1) {
        ss1 += __shfl_xor(ss1, off);
        ss2 += __shfl_xor(ss2, off);
    }
    float sc1 = 1.0f / fmaxf(sqrtf(ss1), 1e-12f);
    float sc2 = 1.0f / fmaxf(sqrtf(ss2), 1e-12f);

    union { __hip_bfloat16 h[4]; short4 s4; } u1, u2;
    u1.h[0] = __float2bfloat16(v1.x * sc1); u1.h[1] = __float2bfloat16(v1.y * sc1);
    u1.h[2] = __float2bfloat16(v1.z * sc1); u1.h[3] = __float2bfloat16(v1.w * sc1);
    u2.h[0] = __float2bfloat16(v2.x * sc2); u2.h[1] = __float2bfloat16(v2.y * sc2);
    u2.h[2] = __float2bfloat16(v2.z * sc2); u2.h[3] = __float2bfloat16(v2.w * sc2);
    ((short4*)(z + (size_t)p * D))[lane]            = u1.s4;
    ((short4*)(z + (size_t)(p + B_ROWS) * D))[lane] = u2.s4;

    float sd1 = 0.f, sd2 = 0.f, dp = 0.f;
#pragma unroll
    for (int j = 0; j < 4; j++) {
        float a = __bfloat162float(u1.h[j]);
        float b = __bfloat162float(u2.h[j]);
        sd1 += a * a; sd2 += b * b; dp += a * b;
    }
#pragma unroll
    for (int off = 32; off > 0; off >>= 1) {
        sd1 += __shfl_xor(sd1, off);
        sd2 += __shfl_xor(sd2, off);
        dp  += __shfl_xor(dp,  off);
    }
    if (lane == 0) {
        pos[p] = dp; pos[p + B_ROWS] = dp;
        selfdot[p] = sd1; selfdot[p + B_ROWS] = sd2;
    }
}

// ---------------------------------------------------------------------------
// Kernel 2 v3: round-0 geometry (512 blocks, 64 rows/wave, A=128 regs) +
//   (a) global_load_lds staging (validated in round 3): frees pf[4] regs and
//       the writeB VALU phase -> deeper B-frag pipelining in the kk loop;
//   (b) mirror col-sums accumulate in LDS (ds-atomics, lgkmcnt domain) and
//       flush to global ONCE per block -> per-tile barrier no longer waits
//       on contended global atomic RMWs (vmcnt drain is staging-only).
// ---------------------------------------------------------------------------
__global__ __launch_bounds__(256, 2) void sim_rowsum_kernel(
    const short* __restrict__ z, float* __restrict__ rowsum,
    const float* __restrict__ pos, const float* __restrict__ selfdot,
    unsigned int* __restrict__ counter, float* __restrict__ out) {
    __shared__ __align__(16) short Bbuf[2][8192];   // 2 x 16 KB
    __shared__ float mirror_lds[MAXT][32];          // per-tile col sums
    __shared__ unsigned int done_s;
    __shared__ float sdata[4];

    const int tid  = threadIdx.x;
    const int lane = tid & 63;
    const int w    = tid >> 6;
    const int lm   = lane & 15;
    const int lg   = lane >> 4;
    const int fxor = lm & 7;

    const int s   = blockIdx.x >> 5;    // strip-pair 0..15
    const int q   = blockIdx.x & 31;    // segment 0..31
    const int L0  = 256 - 8 * s;        // tiles in first strip (panel s)
    const int cb  = (q * TT) >> 5;
    const int ce  = ((q + 1) * TT) >> 5;

    bf16x8 a[8][4];                     // A panel: 64 rows x 256 K (128 regs)
    floatx4 acc[4][2];
    float rsacc[4][4];

#pragma unroll
    for (int mi = 0; mi < 4; mi++)
#pragma unroll
        for (int r = 0; r < 4; r++) rsacc[mi][r] = 0.f;

    // ---- decode tile c -> (panel, colbase, mirror) ----
    auto decode = [&](int c, int& panel, int& colbase, bool& mirror) {
        int cloc;
        if (c < L0) { panel = s;      cloc = c; }
        else        { panel = 31 - s; cloc = c - L0; }
        colbase = panel * 256 + cloc * 32;
        mirror  = (cloc >= 8);
    };

    auto decodeCol = [&](int c) {
        int cloc, panel;
        if (c < L0) { panel = s;      cloc = c; }
        else        { panel = 31 - s; cloc = c - L0; }
        return panel * 256 + cloc * 32;
    };

    auto loadA = [&](int panel) {
#pragma unroll
        for (int kk = 0; kk < 8; kk++)
#pragma unroll
            for (int mi = 0; mi < 4; mi++)
                a[kk][mi] = *(const bf16x8*)(
                    z + (size_t)(panel * 256 + w * 64 + mi * 16 + lm) * D +
                    kk * 32 + lg * 8);
    };

    auto flushRs = [&](int panel) {
#pragma unroll
        for (int mi = 0; mi < 4; mi++)
#pragma unroll
            for (int r = 0; r < 4; r++) {
                float v = rsacc[mi][r];
                v += __shfl_xor(v, 1); v += __shfl_xor(v, 2);
                v += __shfl_xor(v, 4); v += __shfl_xor(v, 8);
                if (lm == 0)
                    atomicAdd(&rowsum[panel * 256 + w * 64 + mi * 16 + lg * 4 + r], v);
                rsacc[mi][r] = 0.f;
            }
    };

    // async stage: 4 x 16B per thread; LDS dest linear, source pre-swizzled so
    // LDS unit u = col*32 + (c16 ^ (col&7)) holds data[col][c16].
    // (validated: round-3 passed with absmax 0)
    auto stage = [&](int buf, int colbase) {
#pragma unroll
        for (int j = 0; j < 4; j++) {
            int col = w * 8 + j * 2 + (lane >> 5);
            int c16 = (lane & 31) ^ (col & 7);
            const short* src = z + (size_t)(colbase + col) * D + c16 * 8;
            __builtin_amdgcn_global_load_lds(
                (const __attribute__((address_space(1))) unsigned int*)src,
                (__attribute__((address_space(3))) unsigned int*)
                    &Bbuf[buf][(w * 4 + j) * 512],
                16, 0, 0);
        }
    };

    // ---- prologue: zero mirror accum, stage first tile, load A panel ----
    for (int e = tid; e < MAXT * 32; e += 256)
        ((float*)mirror_lds)[e] = 0.f;

    int panel, colbase; bool mirror;
    decode(cb, panel, colbase, mirror);
    int curpanel = panel;
    stage(0, colbase);
    loadA(panel);
    __syncthreads();

    for (int c = cb; c < ce; c++) {
        const int buf = (c - cb) & 1;
        decode(c, panel, colbase, mirror);

        if (c + 1 < ce)                   // prefetch next tile into other buffer
            stage(buf ^ 1, decodeCol(c + 1));

        if (panel != curpanel) {          // strip change (<=1 per block)
            flushRs(curpanel);
            loadA(panel);
            curpanel = panel;
        }

#pragma unroll
        for (int mi = 0; mi < 4; mi++)
#pragma unroll
            for (int ni = 0; ni < 2; ni++)
                acc[mi][ni] = (floatx4){0.f, 0.f, 0.f, 0.f};

#pragma unroll
        for (int kk = 0; kk < 8; kk++) {
            bf16x8 b0 = *(const bf16x8*)(
                &Bbuf[buf][((lm) * 32 + ((kk * 4 + lg) ^ fxor)) * 8]);
            bf16x8 b1 = *(const bf16x8*)(
                &Bbuf[buf][((16 + lm) * 32 + ((kk * 4 + lg) ^ fxor)) * 8]);
#pragma unroll
            for (int mi = 0; mi < 4; mi++)
                acc[mi][0] = __builtin_amdgcn_mfma_f32_16x16x32_bf16(
                    a[kk][mi], b0, acc[mi][0], 0, 0, 0);
#pragma unroll
            for (int mi = 0; mi < 4; mi++)
                acc[mi][1] = __builtin_amdgcn_mfma_f32_16x16x32_bf16(
                    a[kk][mi], b1, acc[mi][1], 0, 0, 0);
        }

        // epilogue: exp(2*sim) -> register row-sums (+ mirror col-sums to LDS)
        float cs0 = 0.f, cs1 = 0.f;
#pragma unroll
        for (int mi = 0; mi < 4; mi++)
#pragma unroll
            for (int r = 0; r < 4; r++) {
                float e0 = __expf(2.0f * acc[mi][0][r]);
                float e1 = __expf(2.0f * acc[mi][1][r]);
                rsacc[mi][r] += e0 + e1;
                cs0 += e0; cs1 += e1;
            }
        if (mirror) {
            cs0 += __shfl_xor(cs0, 16); cs0 += __shfl_xor(cs0, 32);
            cs1 += __shfl_xor(cs1, 16); cs1 += __shfl_xor(cs1, 32);
            if (lane < 16) {
                atomicAdd(&mirror_lds[c - cb][lane],      cs0);
                atomicAdd(&mirror_lds[c - cb][16 + lane], cs1);
            }
        }

        __syncthreads();   // drains staging gloads; guards buf reuse
    }
    flushRs(curpanel);

    // ---- flush LDS mirror accumulators to global (once per block) ----
    __syncthreads();
    {
        const int nt = ce - cb;
        for (int e = tid; e < nt * 32; e += 256) {
            int t = e >> 5, col = e & 31;
            int p2, cbase2; bool m2;
            decode(cb + t, p2, cbase2, m2);
            if (m2) atomicAdd(&rowsum[cbase2 + col], mirror_lds[t][col]);
        }
    }

    // ---- last-block-done: final loss ----
    __syncthreads();
    if (tid == 0) {
        __threadfence();
        done_s = atomicAdd(counter, 1u);
    }
    __syncthreads();
    if (done_s == (unsigned int)(NBLK2 - 1)) {
        __threadfence();
        float acc_l = 0.f;
#pragma unroll 4
        for (int r = tid; r < NROWS; r += 256) {
            float rsv = __hip_atomic_load(&rowsum[r], __ATOMIC_RELAXED,
                                          __HIP_MEMORY_SCOPE_AGENT);
            float denom = rsv - __expf(2.0f * selfdot[r]);
            acc_l += -2.0f * pos[r] + logf(denom);
        }
#pragma unroll
        for (int off = 32; off > 0; off >>= 1) acc_l += __shfl_xor(acc_l, off);
        if (lane == 0) sdata[w] = acc_l;
        __syncthreads();
        if (tid == 0)
            out[0] = (sdata[0] + sdata[1] + sdata[2] + sdata[3]) / (float)NROWS;
    }
}

// ---------------------------------------------------------------------------
extern "C" void kernel_launch(void* const* d_in, const int* in_sizes, int n_in,
                              void* d_out, int out_size, void* d_ws, size_t ws_size,
                              hipStream_t stream) {
    const float* xi = (const float*)d_in[0];
    const float* xj = (const float*)d_in[1];
    float* out      = (float*)d_out;

    char* ws        = (char*)d_ws;
    short* z        = (short*)ws;                             // 4 MiB
    float* rowsum   = (float*)(ws + (size_t)NROWS * D * 2);   // 32 KiB
    float* pos      = rowsum + NROWS;                         // 32 KiB
    float* selfdot  = pos + NROWS;                            // 32 KiB
    unsigned int* counter = (unsigned int*)(selfdot + NROWS);

    norm_pos_kernel<<<B_ROWS / 4, 256, 0, stream>>>(xi, xj, z, pos, selfdot,
                                                    rowsum, out, counter);
    sim_rowsum_kernel<<<NBLK2, 256, 0, stream>>>(z, rowsum, pos, selfdot,
                                                 counter, out);
}